// Round 3
// baseline (959.438 us; speedup 1.0000x reference)
//
#include <hip/hip_runtime.h>
#include <stdint.h>

typedef __attribute__((ext_vector_type(8))) short short8;
typedef __attribute__((ext_vector_type(4))) float f32x4;

#define TT 512
#define BB 1024
#define L_STR 136   // ushorts per Z row [h_hi 64 | h_lo 64 | pad 8]; 272 B = 17 16B-chunks (odd -> 2-way max)
#define XS 516      // sX row stride in floats (516 mod 32 = 4 -> spread banks)

__device__ __forceinline__ uint32_t f2bf_u(float f){
  union { float f; uint32_t u; } v; v.f = f;
  return (v.u + 0x7fffu + ((v.u >> 16) & 1u)) >> 16;
}
__device__ __forceinline__ float bf2f(uint32_t w){
  union { uint32_t u; float f; } v; v.u = w << 16; return v.f;
}
__device__ __forceinline__ float fast_rcp(float x){ return __builtin_amdgcn_rcpf(x); }
__device__ __forceinline__ float sigf(float x){ return fast_rcp(1.f + __expf(-x)); }
__device__ __forceinline__ float tanh_f(float x){
  float xx = fminf(fmaxf(x, -10.f), 10.f);
  float e = __expf(2.f * xx);
  return (e - 1.f) * fast_rcp(e + 1.f);
}
__device__ __forceinline__ short8 w8f32(const float* p){
  float4 a = *(const float4*)p;
  float4 b = *(const float4*)(p + 4);
  short8 r;
  r[0] = (short)f2bf_u(a.x); r[1] = (short)f2bf_u(a.y);
  r[2] = (short)f2bf_u(a.z); r[3] = (short)f2bf_u(a.w);
  r[4] = (short)f2bf_u(b.x); r[5] = (short)f2bf_u(b.y);
  r[6] = (short)f2bf_u(b.z); r[7] = (short)f2bf_u(b.w);
  return r;
}
// LDS-only barrier: drain lgkm (ds ops) but leave global loads in flight
// (avoids the vmcnt(0) drain __syncthreads emits before s_barrier).
__device__ __forceinline__ void lds_barrier(){
  asm volatile("s_waitcnt lgkmcnt(0)" ::: "memory");
  __builtin_amdgcn_s_barrier();
}

// ============ Layer 0 ============
__global__ __launch_bounds__(256, 1) void lstm_l0(
    const float* __restrict__ x,   // [B][3][T]
    const float* __restrict__ Wih_f, const float* __restrict__ Whh_f,
    const float* __restrict__ bih_f, const float* __restrict__ bhh_f,
    const float* __restrict__ Wih_b, const float* __restrict__ Whh_b,
    const float* __restrict__ bih_b, const float* __restrict__ bhh_b,
    unsigned short* __restrict__ y0)  // [B][T][128] bf16
{
  const int tid  = threadIdx.x;
  const int wave = tid >> 6, lane = tid & 63;
  const int quad = lane >> 4, m16 = lane & 15;
  const int dir  = blockIdx.y;
  const int bbase = blockIdx.x * 8;
  const float* Wih = dir ? Wih_b : Wih_f;
  const float* Whh = dir ? Whh_b : Whh_f;
  const float* bih = dir ? bih_b : bih_f;
  const float* bhh = dir ? bhh_b : bhh_f;

  __shared__ __align__(16) unsigned short sZ[2][16][L_STR];
  __shared__ float sX[24 * XS];   // 24 rows (3b+d) x 516

  short8 aH[4][2], aX[4];
  f32x4 biasv[4];
  #pragma unroll
  for (int G = 0; G < 4; G++){
    const int row = G * 64 + wave * 16 + m16;
    aH[G][0] = w8f32(Whh + row * 64 + quad * 8);
    aH[G][1] = w8f32(Whh + row * 64 + 32 + quad * 8);
    #pragma unroll
    for (int j = 0; j < 8; j++){
      float w = (quad == 0 && j < 3) ? Wih[row * 3 + j] : 0.f;
      aX[G][j] = (short)f2bf_u(w);
    }
    const int rb = G * 64 + wave * 16 + quad * 4;
    biasv[G][0] = bih[rb + 0] + bhh[rb + 0];
    biasv[G][1] = bih[rb + 1] + bhh[rb + 1];
    biasv[G][2] = bih[rb + 2] + bhh[rb + 2];
    biasv[G][3] = bih[rb + 3] + bhh[rb + 3];
  }

  // zero both h buffers
  for (int idx = tid; idx < 2 * 16 * L_STR; idx += 256)
    ((unsigned short*)sZ)[idx] = 0;
  // stage whole x tile: 24 rows of 512 floats (contiguous slice at bbase*1536)
  for (int i4 = tid; i4 < 3072; i4 += 256){
    const int row = i4 >> 7, t4 = (i4 & 127) * 4;
    float4 v = *(const float4*)(x + (size_t)bbase * 1536 + row * 512 + t4);
    *(float4*)&sX[row * XS + t4] = v;
  }
  lds_barrier();

  const int xrow = 3 * (m16 & 7);
  const f32x4 zz = {0.f, 0.f, 0.f, 0.f};
  float c[4] = {0.f, 0.f, 0.f, 0.f};
  const int u0 = wave * 16 + quad * 4;

  // accX(0)
  f32x4 accX[4];
  {
    const int t0 = dir ? (TT - 1) : 0;
    float x0 = sX[xrow * XS + t0], x1 = sX[(xrow + 1) * XS + t0], x2 = sX[(xrow + 2) * XS + t0];
    short8 bx = {0,0,0,0,0,0,0,0};
    if (quad == 0){ bx[0] = (short)f2bf_u(x0); bx[1] = (short)f2bf_u(x1); bx[2] = (short)f2bf_u(x2); }
    #pragma unroll
    for (int G = 0; G < 4; G++)
      accX[G] = __builtin_amdgcn_mfma_f32_16x16x32_bf16(aX[G], bx, biasv[G], 0, 0, 0);
  }

  for (int s = 0; s < TT; s++){
    const int p = s & 1, p1 = p ^ 1;
    const int t = dir ? (TT - 1 - s) : s;

    short8 bh0 = *(const short8*)&sZ[p][m16][     quad * 8];
    short8 bh1 = *(const short8*)&sZ[p][m16][32 + quad * 8];
    short8 bl0 = *(const short8*)&sZ[p][m16][64 + quad * 8];
    short8 bl1 = *(const short8*)&sZ[p][m16][96 + quad * 8];

    f32x4 acc[4];
    #pragma unroll
    for (int G = 0; G < 4; G++){
      f32x4 aA = __builtin_amdgcn_mfma_f32_16x16x32_bf16(aH[G][0], bh0, accX[G], 0, 0, 0);
      aA       = __builtin_amdgcn_mfma_f32_16x16x32_bf16(aH[G][0], bl0, aA,      0, 0, 0);
      f32x4 aB = __builtin_amdgcn_mfma_f32_16x16x32_bf16(aH[G][1], bh1, zz,      0, 0, 0);
      aB       = __builtin_amdgcn_mfma_f32_16x16x32_bf16(aH[G][1], bl1, aB,      0, 0, 0);
      acc[G] = aA + aB;
    }

    float hval[4];
    #pragma unroll
    for (int r = 0; r < 4; r++){
      float ip = sigf(acc[0][r]);
      float fp = sigf(acc[1][r]);
      float gp = tanh_f(acc[2][r]);
      float op = sigf(acc[3][r]);
      c[r] = fmaf(fp, c[r], ip * gp);
      hval[r] = op * tanh_f(c[r]);
    }
    uint32_t h0 = f2bf_u(hval[0]), h1 = f2bf_u(hval[1]),
             h2 = f2bf_u(hval[2]), h3 = f2bf_u(hval[3]);
    uint32_t l0b = f2bf_u(hval[0] - bf2f(h0)), l1b = f2bf_u(hval[1] - bf2f(h1)),
             l2b = f2bf_u(hval[2] - bf2f(h2)), l3b = f2bf_u(hval[3] - bf2f(h3));

    *(uint2*)&sZ[p1][m16][u0]      = make_uint2(h0  | (h1 << 16), h2  | (h3 << 16));
    *(uint2*)&sZ[p1][m16][64 + u0] = make_uint2(l0b | (l1b << 16), l2b | (l3b << 16));
    if (m16 < 8){
      *(uint2*)(y0 + ((size_t)(bbase + m16) * TT + t) * 128 + dir * 64 + u0) =
          make_uint2(h0 | (h1 << 16), h2 | (h3 << 16));
    }

    // shadow: accX for step s+1 (from LDS-staged x; off the critical path)
    {
      const int sn = (s + 1 < TT) ? (s + 1) : s;
      const int tn = dir ? (TT - 1 - sn) : sn;
      float x0 = sX[xrow * XS + tn], x1 = sX[(xrow + 1) * XS + tn], x2 = sX[(xrow + 2) * XS + tn];
      short8 bx = {0,0,0,0,0,0,0,0};
      if (quad == 0){ bx[0] = (short)f2bf_u(x0); bx[1] = (short)f2bf_u(x1); bx[2] = (short)f2bf_u(x2); }
      #pragma unroll
      for (int G = 0; G < 4; G++)
        accX[G] = __builtin_amdgcn_mfma_f32_16x16x32_bf16(aX[G], bx, biasv[G], 0, 0, 0);
    }
    lds_barrier();
  }
}

// ============ Layer 1 ============
__global__ __launch_bounds__(256, 1) void lstm_l1(
    const unsigned short* __restrict__ y0,  // [B][T][128] bf16
    const float* __restrict__ Wih_f, const float* __restrict__ Whh_f,
    const float* __restrict__ bih_f, const float* __restrict__ bhh_f,
    const float* __restrict__ Wih_b, const float* __restrict__ Whh_b,
    const float* __restrict__ bih_b, const float* __restrict__ bhh_b,
    float* __restrict__ hT)                 // [B][128] fp32
{
  const int tid  = threadIdx.x;
  const int wave = tid >> 6, lane = tid & 63;
  const int quad = lane >> 4, m16 = lane & 15;
  const int dir  = blockIdx.y;
  const int bbase = blockIdx.x * 8;
  const float* Wih = dir ? Wih_b : Wih_f;
  const float* Whh = dir ? Whh_b : Whh_f;
  const float* bih = dir ? bih_b : bih_f;
  const float* bhh = dir ? bhh_b : bhh_f;

  __shared__ __align__(16) unsigned short sZ[2][16][L_STR];

  short8 aY[4][4], aH[4][2];
  f32x4 biasv[4];
  #pragma unroll
  for (int G = 0; G < 4; G++){
    const int row = G * 64 + wave * 16 + m16;
    #pragma unroll
    for (int kt = 0; kt < 4; kt++)
      aY[G][kt] = w8f32(Wih + row * 128 + kt * 32 + quad * 8);
    aH[G][0] = w8f32(Whh + row * 64 + quad * 8);
    aH[G][1] = w8f32(Whh + row * 64 + 32 + quad * 8);
    const int rb = G * 64 + wave * 16 + quad * 4;
    biasv[G][0] = bih[rb + 0] + bhh[rb + 0];
    biasv[G][1] = bih[rb + 1] + bhh[rb + 1];
    biasv[G][2] = bih[rb + 2] + bhh[rb + 2];
    biasv[G][3] = bih[rb + 3] + bhh[rb + 3];
  }

  for (int idx = tid; idx < 2 * 16 * L_STR; idx += 256)
    ((unsigned short*)sZ)[idx] = 0;
  lds_barrier();

  const size_t brow = (size_t)(bbase + (m16 & 7)) * TT;
  const f32x4 zz = {0.f, 0.f, 0.f, 0.f};
  float c[4] = {0.f, 0.f, 0.f, 0.f};
  const int u0 = wave * 16 + quad * 4;

  // accY(0) + 2-deep prefetch
  f32x4 accY[4];
  short8 byn[4], byn2[4];
  {
    const int t0 = dir ? (TT - 1) : 0;
    const unsigned short* yb = y0 + (brow + t0) * 128;
    short8 b0 = *(const short8*)(yb +       quad * 8);
    short8 b1 = *(const short8*)(yb + 32  + quad * 8);
    short8 b2 = *(const short8*)(yb + 64  + quad * 8);
    short8 b3 = *(const short8*)(yb + 96  + quad * 8);
    #pragma unroll
    for (int G = 0; G < 4; G++){
      f32x4 a = biasv[G];
      a = __builtin_amdgcn_mfma_f32_16x16x32_bf16(aY[G][0], b0, a, 0, 0, 0);
      a = __builtin_amdgcn_mfma_f32_16x16x32_bf16(aY[G][1], b1, a, 0, 0, 0);
      a = __builtin_amdgcn_mfma_f32_16x16x32_bf16(aY[G][2], b2, a, 0, 0, 0);
      a = __builtin_amdgcn_mfma_f32_16x16x32_bf16(aY[G][3], b3, a, 0, 0, 0);
      accY[G] = a;
    }
    const int t1 = dir ? (TT - 2) : 1;
    const int t2 = dir ? (TT - 3) : 2;
    const unsigned short* y1 = y0 + (brow + t1) * 128;
    const unsigned short* y2 = y0 + (brow + t2) * 128;
    #pragma unroll
    for (int kt = 0; kt < 4; kt++){
      byn[kt]  = *(const short8*)(y1 + kt * 32 + quad * 8);
      byn2[kt] = *(const short8*)(y2 + kt * 32 + quad * 8);
    }
  }

  for (int s = 0; s < TT; s++){
    const int p = s & 1, p1 = p ^ 1;

    short8 bh0 = *(const short8*)&sZ[p][m16][     quad * 8];
    short8 bh1 = *(const short8*)&sZ[p][m16][32 + quad * 8];
    short8 bl0 = *(const short8*)&sZ[p][m16][64 + quad * 8];
    short8 bl1 = *(const short8*)&sZ[p][m16][96 + quad * 8];

    f32x4 acc[4];
    #pragma unroll
    for (int G = 0; G < 4; G++){
      f32x4 aA = __builtin_amdgcn_mfma_f32_16x16x32_bf16(aH[G][0], bh0, accY[G], 0, 0, 0);
      aA       = __builtin_amdgcn_mfma_f32_16x16x32_bf16(aH[G][0], bl0, aA,      0, 0, 0);
      f32x4 aB = __builtin_amdgcn_mfma_f32_16x16x32_bf16(aH[G][1], bh1, zz,      0, 0, 0);
      aB       = __builtin_amdgcn_mfma_f32_16x16x32_bf16(aH[G][1], bl1, aB,      0, 0, 0);
      acc[G] = aA + aB;
    }

    float hval[4];
    #pragma unroll
    for (int r = 0; r < 4; r++){
      float ip = sigf(acc[0][r]);
      float fp = sigf(acc[1][r]);
      float gp = tanh_f(acc[2][r]);
      float op = sigf(acc[3][r]);
      c[r] = fmaf(fp, c[r], ip * gp);
      hval[r] = op * tanh_f(c[r]);
    }
    uint32_t h0 = f2bf_u(hval[0]), h1 = f2bf_u(hval[1]),
             h2 = f2bf_u(hval[2]), h3 = f2bf_u(hval[3]);
    uint32_t l0b = f2bf_u(hval[0] - bf2f(h0)), l1b = f2bf_u(hval[1] - bf2f(h1)),
             l2b = f2bf_u(hval[2] - bf2f(h2)), l3b = f2bf_u(hval[3] - bf2f(h3));

    *(uint2*)&sZ[p1][m16][u0]      = make_uint2(h0  | (h1 << 16), h2  | (h3 << 16));
    *(uint2*)&sZ[p1][m16][64 + u0] = make_uint2(l0b | (l1b << 16), l2b | (l3b << 16));

    if (s == TT - 1 && m16 < 8){
      float4 hv; hv.x = hval[0]; hv.y = hval[1]; hv.z = hval[2]; hv.w = hval[3];
      *(float4*)(hT + (size_t)(bbase + m16) * 128 + dir * 64 + u0) = hv;
    }

    // shadow: accY for step s+1 from prefetched frags; rotate; issue load for s+3
    #pragma unroll
    for (int G = 0; G < 4; G++){
      f32x4 a = biasv[G];
      a = __builtin_amdgcn_mfma_f32_16x16x32_bf16(aY[G][0], byn[0], a, 0, 0, 0);
      a = __builtin_amdgcn_mfma_f32_16x16x32_bf16(aY[G][1], byn[1], a, 0, 0, 0);
      a = __builtin_amdgcn_mfma_f32_16x16x32_bf16(aY[G][2], byn[2], a, 0, 0, 0);
      a = __builtin_amdgcn_mfma_f32_16x16x32_bf16(aY[G][3], byn[3], a, 0, 0, 0);
      accY[G] = a;
    }
    {
      #pragma unroll
      for (int kt = 0; kt < 4; kt++) byn[kt] = byn2[kt];
      const int sn = (s + 3 < TT) ? (s + 3) : (TT - 1);
      const int tn = dir ? (TT - 1 - sn) : sn;
      const unsigned short* yb = y0 + (brow + tn) * 128;
      #pragma unroll
      for (int kt = 0; kt < 4; kt++) byn2[kt] = *(const short8*)(yb + kt * 32 + quad * 8);
    }
    lds_barrier();
  }
}

// ============ FC head ============
__global__ __launch_bounds__(256, 1) void fc_kernel(
    const float* __restrict__ hT,
    const float* __restrict__ w1, const float* __restrict__ b1,
    const float* __restrict__ w2, const float* __restrict__ b2,
    float* __restrict__ out)
{
  __shared__ float sh[4][64];
  const int wave = threadIdx.x >> 6, lane = threadIdx.x & 63;
  const int b = blockIdx.x * 4 + wave;
  float acc = b1[lane];
  const float* hrow = hT + (size_t)b * 128;
  #pragma unroll
  for (int k = 0; k < 128; k += 4){
    float4 h4 = *(const float4*)(hrow + k);
    float4 w4 = *(const float4*)(w1 + lane * 128 + k);
    acc = fmaf(w4.x, h4.x, acc);
    acc = fmaf(w4.y, h4.y, acc);
    acc = fmaf(w4.z, h4.z, acc);
    acc = fmaf(w4.w, h4.w, acc);
  }
  sh[wave][lane] = fmaxf(acc, 0.f);
  __syncthreads();
  if (lane < 2){
    float a = b2[lane];
    #pragma unroll
    for (int k = 0; k < 64; k++) a = fmaf(w2[lane * 64 + k], sh[wave][k], a);
    out[(size_t)b * 2 + lane] = a;
  }
}

extern "C" void kernel_launch(void* const* d_in, const int* in_sizes, int n_in,
                              void* d_out, int out_size, void* d_ws, size_t ws_size,
                              hipStream_t stream){
  (void)in_sizes; (void)n_in; (void)out_size; (void)ws_size;
  const float* x     = (const float*)d_in[0];
  const float* Wih0f = (const float*)d_in[1];
  const float* Whh0f = (const float*)d_in[2];
  const float* bih0f = (const float*)d_in[3];
  const float* bhh0f = (const float*)d_in[4];
  const float* Wih0b = (const float*)d_in[5];
  const float* Whh0b = (const float*)d_in[6];
  const float* bih0b = (const float*)d_in[7];
  const float* bhh0b = (const float*)d_in[8];
  const float* Wih1f = (const float*)d_in[9];
  const float* Whh1f = (const float*)d_in[10];
  const float* bih1f = (const float*)d_in[11];
  const float* bhh1f = (const float*)d_in[12];
  const float* Wih1b = (const float*)d_in[13];
  const float* Whh1b = (const float*)d_in[14];
  const float* bih1b = (const float*)d_in[15];
  const float* bhh1b = (const float*)d_in[16];
  const float* fc1W  = (const float*)d_in[17];
  const float* fc1b  = (const float*)d_in[18];
  const float* fc2W  = (const float*)d_in[19];
  const float* fc2b  = (const float*)d_in[20];
  float* out = (float*)d_out;

  unsigned short* y0 = (unsigned short*)d_ws;                  // 134,217,728 B
  float* hT = (float*)((char*)d_ws + (size_t)BB * TT * 128 * 2);

  dim3 grid(BB / 8, 2), block(256);
  lstm_l0<<<grid, block, 0, stream>>>(x, Wih0f, Whh0f, bih0f, bhh0f,
                                      Wih0b, Whh0b, bih0b, bhh0b, y0);
  lstm_l1<<<grid, block, 0, stream>>>(y0, Wih1f, Whh1f, bih1f, bhh1f,
                                      Wih1b, Whh1b, bih1b, bhh1b, hT);
  fc_kernel<<<dim3(BB / 4), block, 0, stream>>>(hT, fc1W, fc1b, fc2W, fc2b, out);
}

// Round 4
// 808.265 us; speedup vs baseline: 1.1870x; 1.1870x over previous
//
#include <hip/hip_runtime.h>
#include <stdint.h>

typedef __attribute__((ext_vector_type(8))) short short8;
typedef __attribute__((ext_vector_type(4))) float f32x4;

#define TT 512
#define LSTR 136   // sZ/sY row stride in ushorts: 272B (68 dw) -> spread banks
#define XS 516     // sX row stride in floats

static __device__ __forceinline__ uint32_t f2bf_u(float f){
  union { float f; uint32_t u; } v; v.f = f;
  return (v.u + 0x7fffu + ((v.u >> 16) & 1u)) >> 16;
}
static __device__ __forceinline__ float bf2f(uint32_t w){
  union { uint32_t u; float f; } v; v.u = w << 16; return v.f;
}
static __device__ __forceinline__ float fast_rcp(float x){ return __builtin_amdgcn_rcpf(x); }
static __device__ __forceinline__ float sigf(float x){ return fast_rcp(1.f + __expf(-x)); }
static __device__ __forceinline__ float tanh_f(float x){
  float xx = fminf(fmaxf(x, -10.f), 10.f);
  float e = __expf(2.f * xx);
  return (e - 1.f) * fast_rcp(e + 1.f);
}
static __device__ __forceinline__ short8 w8f32(const float* p){
  float4 a = *(const float4*)p;
  float4 b = *(const float4*)(p + 4);
  short8 r;
  r[0] = (short)f2bf_u(a.x); r[1] = (short)f2bf_u(a.y);
  r[2] = (short)f2bf_u(a.z); r[3] = (short)f2bf_u(a.w);
  r[4] = (short)f2bf_u(b.x); r[5] = (short)f2bf_u(b.y);
  r[6] = (short)f2bf_u(b.z); r[7] = (short)f2bf_u(b.w);
  return r;
}
// LDS-only barrier: waits ds ops, leaves global loads/stores in flight.
static __device__ __forceinline__ void lds_barrier(){
  asm volatile("s_waitcnt lgkmcnt(0)" ::: "memory");
  __builtin_amdgcn_s_barrier();
}
#define MF(A,B,C) __builtin_amdgcn_mfma_f32_16x16x32_bf16((A),(B),(C),0,0,0)

// ==================== Layer 0 ====================
// 512 thr / 8 waves; wave w owns rowtiles 2w,2w+1 (units 8w+q, 8w+4+q per lane quad q)
__global__ __launch_bounds__(512, 2) void lstm_l0(
    const float* __restrict__ x,   // [B][3][T]
    const float* __restrict__ Wih_f, const float* __restrict__ Whh_f,
    const float* __restrict__ bih_f, const float* __restrict__ bhh_f,
    const float* __restrict__ Wih_b, const float* __restrict__ Whh_b,
    const float* __restrict__ bih_b, const float* __restrict__ bhh_b,
    unsigned short* __restrict__ y0)  // [B][T][128] bf16
{
  const int tid = threadIdx.x;
  const int wv = tid >> 6, lane = tid & 63;
  const int quad = lane >> 4, m16 = lane & 15;
  const int dir = blockIdx.y;
  const int bbase = blockIdx.x * 8;
  const float* Wih = dir ? Wih_b : Wih_f;
  const float* Whh = dir ? Whh_b : Whh_f;
  const float* bih = dir ? bih_b : bih_f;
  const float* bhh = dir ? bhh_b : bhh_f;

  __shared__ __align__(16) unsigned short sZ[2][16][LSTR];
  __shared__ __align__(16) float sX[24 * XS];

  // A-frags: tile-row rho -> gate (rho&3), unit 4*rt+(rho>>2). Lane's A row: rho=m16, k=quad*8+j.
  short8 aH[2][2], aX[2];
  f32x4 biasv[2];
  const int gm = (m16 & 3) * 64 + (m16 >> 2);
  #pragma unroll
  for (int i = 0; i < 2; i++){
    const int rt = 2 * wv + i;
    const int g = gm + 4 * rt;
    aH[i][0] = w8f32(Whh + g * 64 + quad * 8);
    aH[i][1] = w8f32(Whh + g * 64 + 32 + quad * 8);
    short8 ax = {0,0,0,0,0,0,0,0};
    if (quad == 0){
      ax[0] = (short)f2bf_u(Wih[g * 3 + 0]);
      ax[1] = (short)f2bf_u(Wih[g * 3 + 1]);
      ax[2] = (short)f2bf_u(Wih[g * 3 + 2]);
    }
    aX[i] = ax;
    const int gu = 4 * rt + quad;   // C reg r -> gate row r*64 + gu
    #pragma unroll
    for (int r = 0; r < 4; r++) biasv[i][r] = bih[r * 64 + gu] + bhh[r * 64 + gu];
  }

  for (int idx = tid; idx < 2 * 16 * LSTR; idx += 512)
    ((unsigned short*)sZ)[idx] = 0;
  for (int i4 = tid; i4 < 3072; i4 += 512){
    const int row = i4 >> 7, t4 = (i4 & 127) * 4;
    *(float4*)&sX[row * XS + t4] = *(const float4*)(x + (size_t)bbase * 1536 + row * 512 + t4);
  }
  __syncthreads();

  const int xrow = 3 * (m16 & 7);
  float c0 = 0.f, c1 = 0.f;

  for (int s = 0; s < TT; s++){
    const int p = s & 1, p1 = p ^ 1;
    const int t = dir ? (TT - 1 - s) : s;

    short8 bh0 = *(const short8*)&sZ[p][m16][     quad * 8];
    short8 bh1 = *(const short8*)&sZ[p][m16][32 + quad * 8];
    short8 bl0 = *(const short8*)&sZ[p][m16][64 + quad * 8];
    short8 bl1 = *(const short8*)&sZ[p][m16][96 + quad * 8];
    short8 bx = {0,0,0,0,0,0,0,0};
    if (quad == 0){
      bx[0] = (short)f2bf_u(sX[xrow * XS + t]);
      bx[1] = (short)f2bf_u(sX[(xrow + 1) * XS + t]);
      bx[2] = (short)f2bf_u(sX[(xrow + 2) * XS + t]);
    }

    // wave 7: store previous step's h row (committed in sZ[p]) to y0, coalesced
    if (wv == 7 && s > 0){
      const int tprev = dir ? (TT - s) : (s - 1);
      const int br = lane >> 3, cc = lane & 7;
      short8 v = *(const short8*)&sZ[p][br][cc * 8];
      *(short8*)(y0 + ((size_t)(bbase + br) * TT + tprev) * 128 + dir * 64 + cc * 8) = v;
    }

    f32x4 a0 = biasv[0], a1 = biasv[1];
    a0 = MF(aH[0][0], bh0, a0);  a1 = MF(aH[1][0], bh0, a1);
    a0 = MF(aH[0][1], bh1, a0);  a1 = MF(aH[1][1], bh1, a1);
    a0 = MF(aH[0][0], bl0, a0);  a1 = MF(aH[1][0], bl0, a1);
    a0 = MF(aH[0][1], bl1, a0);  a1 = MF(aH[1][1], bl1, a1);
    a0 = MF(aX[0],    bx,  a0);  a1 = MF(aX[1],    bx,  a1);

    float h0, h1;
    {
      float ip = sigf(a0[0]), fp = sigf(a0[1]), gp = tanh_f(a0[2]), op = sigf(a0[3]);
      c0 = fmaf(fp, c0, ip * gp); h0 = op * tanh_f(c0);
    }
    {
      float ip = sigf(a1[0]), fp = sigf(a1[1]), gp = tanh_f(a1[2]), op = sigf(a1[3]);
      c1 = fmaf(fp, c1, ip * gp); h1 = op * tanh_f(c1);
    }
    if (m16 < 8){
      const int u0 = 8 * wv + quad, u1 = u0 + 4;
      uint32_t hh0 = f2bf_u(h0), hh1 = f2bf_u(h1);
      sZ[p1][m16][u0] = (unsigned short)hh0;
      sZ[p1][m16][u1] = (unsigned short)hh1;
      sZ[p1][m16][64 + u0] = (unsigned short)f2bf_u(h0 - bf2f(hh0));
      sZ[p1][m16][64 + u1] = (unsigned short)f2bf_u(h1 - bf2f(hh1));
    }
    lds_barrier();
  }
  // final timestep's h
  if (wv == 7){
    const int tl = dir ? 0 : (TT - 1);
    const int br = lane >> 3, cc = lane & 7;
    short8 v = *(const short8*)&sZ[0][br][cc * 8];
    *(short8*)(y0 + ((size_t)(bbase + br) * TT + tl) * 128 + dir * 64 + cc * 8) = v;
  }
}

// ==================== Layer 1 ====================
__global__ __launch_bounds__(512, 2) void lstm_l1(
    const unsigned short* __restrict__ y0,  // [B][T][128] bf16
    const float* __restrict__ Wih_f, const float* __restrict__ Whh_f,
    const float* __restrict__ bih_f, const float* __restrict__ bhh_f,
    const float* __restrict__ Wih_b, const float* __restrict__ Whh_b,
    const float* __restrict__ bih_b, const float* __restrict__ bhh_b,
    float* __restrict__ hT)                 // [B][128] fp32
{
  const int tid = threadIdx.x;
  const int wv = tid >> 6, lane = tid & 63;
  const int quad = lane >> 4, m16 = lane & 15;
  const int dir = blockIdx.y;
  const int bbase = blockIdx.x * 8;
  const float* Wih = dir ? Wih_b : Wih_f;
  const float* Whh = dir ? Whh_b : Whh_f;
  const float* bih = dir ? bih_b : bih_f;
  const float* bhh = dir ? bhh_b : bhh_f;

  __shared__ __align__(16) unsigned short sZ[2][16][LSTR];
  __shared__ __align__(16) unsigned short sY[4][8][LSTR];   // 4-slot y0 ring

  short8 aY[2][4], aH[2][2];
  f32x4 biasv[2];
  const int gm = (m16 & 3) * 64 + (m16 >> 2);
  #pragma unroll
  for (int i = 0; i < 2; i++){
    const int rt = 2 * wv + i;
    const int g = gm + 4 * rt;
    #pragma unroll
    for (int kt = 0; kt < 4; kt++) aY[i][kt] = w8f32(Wih + g * 128 + kt * 32 + quad * 8);
    aH[i][0] = w8f32(Whh + g * 64 + quad * 8);
    aH[i][1] = w8f32(Whh + g * 64 + 32 + quad * 8);
    const int gu = 4 * rt + quad;
    #pragma unroll
    for (int r = 0; r < 4; r++) biasv[i][r] = bih[r * 64 + gu] + bhh[r * 64 + gu];
  }

  for (int idx = tid; idx < 2 * 16 * LSTR; idx += 512)
    ((unsigned short*)sZ)[idx] = 0;

  // staging lanes (waves 0-1): task = tid in [0,128): row=tid>>4, chunk=tid&15
  const int srow = tid >> 4, schunk = tid & 15;
  const size_t sgbase = (size_t)(bbase + (srow & 7)) * TT * 128 + schunk * 8;
  float4 hA = make_float4(0.f,0.f,0.f,0.f), hB = make_float4(0.f,0.f,0.f,0.f);
  if (wv < 2){
    const int t0 = dir ? (TT-1) : 0, t1 = dir ? (TT-2) : 1, t2 = dir ? (TT-3) : 2;
    const int t3 = dir ? (TT-4) : 3, t4 = dir ? (TT-5) : 4;
    float4 v0 = *(const float4*)(y0 + sgbase + (size_t)t0 * 128);
    float4 v1 = *(const float4*)(y0 + sgbase + (size_t)t1 * 128);
    float4 v2 = *(const float4*)(y0 + sgbase + (size_t)t2 * 128);
    hA = *(const float4*)(y0 + sgbase + (size_t)t3 * 128);
    hB = *(const float4*)(y0 + sgbase + (size_t)t4 * 128);
    *(float4*)&sY[0][srow][schunk * 8] = v0;
    *(float4*)&sY[1][srow][schunk * 8] = v1;
    *(float4*)&sY[2][srow][schunk * 8] = v2;
  }
  __syncthreads();

  const int m8 = m16 & 7;
  float c0 = 0.f, c1 = 0.f;

#define L1STEP(S, HOLD) do { \
    const int p = (S) & 1, p1 = p ^ 1, slot = (S) & 3; \
    if (wv < 2){ \
      *(float4*)&sY[((S) + 3) & 3][srow][schunk * 8] = HOLD; \
      int sg = (S) + 5; if (sg > TT - 1) sg = TT - 1; \
      const int tg = dir ? (TT - 1 - sg) : sg; \
      HOLD = *(const float4*)(y0 + sgbase + (size_t)tg * 128); \
    } \
    short8 bh0 = *(const short8*)&sZ[p][m16][     quad * 8]; \
    short8 bh1 = *(const short8*)&sZ[p][m16][32 + quad * 8]; \
    short8 bl0 = *(const short8*)&sZ[p][m16][64 + quad * 8]; \
    short8 bl1 = *(const short8*)&sZ[p][m16][96 + quad * 8]; \
    short8 by0 = *(const short8*)&sY[slot][m8][     quad * 8]; \
    short8 by1 = *(const short8*)&sY[slot][m8][32 + quad * 8]; \
    short8 by2 = *(const short8*)&sY[slot][m8][64 + quad * 8]; \
    short8 by3 = *(const short8*)&sY[slot][m8][96 + quad * 8]; \
    f32x4 a0 = biasv[0], a1 = biasv[1]; \
    a0 = MF(aY[0][0], by0, a0);  a1 = MF(aY[1][0], by0, a1); \
    a0 = MF(aY[0][1], by1, a0);  a1 = MF(aY[1][1], by1, a1); \
    a0 = MF(aY[0][2], by2, a0);  a1 = MF(aY[1][2], by2, a1); \
    a0 = MF(aY[0][3], by3, a0);  a1 = MF(aY[1][3], by3, a1); \
    a0 = MF(aH[0][0], bh0, a0);  a1 = MF(aH[1][0], bh0, a1); \
    a0 = MF(aH[0][1], bh1, a0);  a1 = MF(aH[1][1], bh1, a1); \
    a0 = MF(aH[0][0], bl0, a0);  a1 = MF(aH[1][0], bl0, a1); \
    a0 = MF(aH[0][1], bl1, a0);  a1 = MF(aH[1][1], bl1, a1); \
    float h0, h1; \
    { float ip = sigf(a0[0]), fp = sigf(a0[1]), gp = tanh_f(a0[2]), op = sigf(a0[3]); \
      c0 = fmaf(fp, c0, ip * gp); h0 = op * tanh_f(c0); } \
    { float ip = sigf(a1[0]), fp = sigf(a1[1]), gp = tanh_f(a1[2]), op = sigf(a1[3]); \
      c1 = fmaf(fp, c1, ip * gp); h1 = op * tanh_f(c1); } \
    if (m16 < 8){ \
      const int u0 = 8 * wv + quad, u1 = u0 + 4; \
      uint32_t hh0 = f2bf_u(h0), hh1 = f2bf_u(h1); \
      sZ[p1][m16][u0] = (unsigned short)hh0; \
      sZ[p1][m16][u1] = (unsigned short)hh1; \
      sZ[p1][m16][64 + u0] = (unsigned short)f2bf_u(h0 - bf2f(hh0)); \
      sZ[p1][m16][64 + u1] = (unsigned short)f2bf_u(h1 - bf2f(hh1)); \
      if ((S) == TT - 1){ \
        hT[(size_t)(bbase + m16) * 128 + dir * 64 + u0] = h0; \
        hT[(size_t)(bbase + m16) * 128 + dir * 64 + u1] = h1; \
      } \
    } \
    lds_barrier(); \
  } while(0)

  for (int s = 0; s < TT; s += 2){
    L1STEP(s, hA);
    L1STEP(s + 1, hB);
  }
#undef L1STEP
}

// ==================== FC head ====================
__global__ __launch_bounds__(256, 1) void fc_kernel(
    const float* __restrict__ hT,
    const float* __restrict__ w1, const float* __restrict__ b1,
    const float* __restrict__ w2, const float* __restrict__ b2,
    float* __restrict__ out)
{
  __shared__ float sh[4][64];
  const int wave = threadIdx.x >> 6, lane = threadIdx.x & 63;
  const int b = blockIdx.x * 4 + wave;
  float acc = b1[lane];
  const float* hrow = hT + (size_t)b * 128;
  #pragma unroll
  for (int k = 0; k < 128; k += 4){
    float4 h4 = *(const float4*)(hrow + k);
    float4 w4 = *(const float4*)(w1 + lane * 128 + k);
    acc = fmaf(w4.x, h4.x, acc);
    acc = fmaf(w4.y, h4.y, acc);
    acc = fmaf(w4.z, h4.z, acc);
    acc = fmaf(w4.w, h4.w, acc);
  }
  sh[wave][lane] = fmaxf(acc, 0.f);
  __syncthreads();
  if (lane < 2){
    float a = b2[lane];
    #pragma unroll
    for (int k = 0; k < 64; k++) a = fmaf(w2[lane * 64 + k], sh[wave][k], a);
    out[(size_t)b * 2 + lane] = a;
  }
}

extern "C" void kernel_launch(void* const* d_in, const int* in_sizes, int n_in,
                              void* d_out, int out_size, void* d_ws, size_t ws_size,
                              hipStream_t stream){
  (void)in_sizes; (void)n_in; (void)out_size; (void)ws_size;
  const float* x     = (const float*)d_in[0];
  const float* Wih0f = (const float*)d_in[1];
  const float* Whh0f = (const float*)d_in[2];
  const float* bih0f = (const float*)d_in[3];
  const float* bhh0f = (const float*)d_in[4];
  const float* Wih0b = (const float*)d_in[5];
  const float* Whh0b = (const float*)d_in[6];
  const float* bih0b = (const float*)d_in[7];
  const float* bhh0b = (const float*)d_in[8];
  const float* Wih1f = (const float*)d_in[9];
  const float* Whh1f = (const float*)d_in[10];
  const float* bih1f = (const float*)d_in[11];
  const float* bhh1f = (const float*)d_in[12];
  const float* Wih1b = (const float*)d_in[13];
  const float* Whh1b = (const float*)d_in[14];
  const float* bih1b = (const float*)d_in[15];
  const float* bhh1b = (const float*)d_in[16];
  const float* fc1W  = (const float*)d_in[17];
  const float* fc1b  = (const float*)d_in[18];
  const float* fc2W  = (const float*)d_in[19];
  const float* fc2b  = (const float*)d_in[20];
  float* out = (float*)d_out;

  unsigned short* y0 = (unsigned short*)d_ws;                       // 134,217,728 B
  float* hT = (float*)((char*)d_ws + (size_t)1024 * TT * 128 * 2);

  dim3 grid(128, 2), block(512);
  lstm_l0<<<grid, block, 0, stream>>>(x, Wih0f, Whh0f, bih0f, bhh0f,
                                      Wih0b, Whh0b, bih0b, bhh0b, y0);
  lstm_l1<<<grid, block, 0, stream>>>(y0, Wih1f, Whh1f, bih1f, bhh1f,
                                      Wih1b, Whh1b, bih1b, bhh1b, hT);
  fc_kernel<<<dim3(256), dim3(256), 0, stream>>>(hT, fc1W, fc1b, fc2W, fc2b, out);
}